// Round 1
// baseline (193.727 us; speedup 1.0000x reference)
//
#include <hip/hip_runtime.h>

typedef __attribute__((ext_vector_type(8))) short bf16x8;
typedef __attribute__((ext_vector_type(4))) float f32x4;

// ---------------------------------------------------------------------------
// Posit(8,1) round-to-nearest quantization, bit-exact vs the jnp reference.
// two_es=2, npat=6, maxpos=2^12, minpos=2^-12. Result has <=4 fraction bits ->
// exactly representable in bf16 (and fp32).
// ---------------------------------------------------------------------------
__device__ __forceinline__ float posit_q(float x) {
  float ax = fabsf(x);
  ax = fmaxf(ax, 0x1p-12f);
  ax = fminf(ax, 0x1p12f);
  int s = (int)(__float_as_uint(ax) >> 23) - 127;   // floor(log2(ax)), exact
  int k = s >> 1;                                   // floor(s/2)
  int rlen = (k >= 0) ? (k + 2) : (1 - k);
  int fbits = 6 - rlen;
  fbits = fbits < 0 ? 0 : fbits;
  float m = ax * __uint_as_float((unsigned)(127 - s) << 23);  // [1,2)
  float fs = (float)(1 << fbits);
  float inv_fs = __uint_as_float((unsigned)(127 - fbits) << 23);
  float mq = rintf(m * fs) * inv_fs;                // round-half-even = jnp.round
  if (mq >= 2.0f) { s += 1; mq = 1.0f; }            // mantissa carry
  float y = mq * __uint_as_float((unsigned)(127 + s) << 23);
  y = fminf(y, 0x1p12f);
  y = copysignf(y, x);
  return (x == 0.0f) ? 0.0f : y;
}

__device__ __forceinline__ ushort4 quant4_bf16(float4 v) {
  ushort4 o;
  o.x = (ushort)(__float_as_uint(posit_q(v.x)) >> 16);
  o.y = (ushort)(__float_as_uint(posit_q(v.y)) >> 16);
  o.z = (ushort)(__float_as_uint(posit_q(v.z)) >> 16);
  o.w = (ushort)(__float_as_uint(posit_q(v.w)) >> 16);
  return o;
}

// One merged quantize kernel: x -> bf16, w -> bf16, bias -> fp32.
__global__ void posit_quant_all(const float* __restrict__ x,
                                const float* __restrict__ w,
                                const float* __restrict__ b,
                                ushort* __restrict__ Xq,
                                ushort* __restrict__ Wq,
                                float* __restrict__ bq,
                                int nx4, int nw4, int nb4) {
  int i = blockIdx.x * blockDim.x + threadIdx.x;
  if (i < nx4) {
    ((ushort4*)Xq)[i] = quant4_bf16(((const float4*)x)[i]);
  } else if (i < nx4 + nw4) {
    int j = i - nx4;
    ((ushort4*)Wq)[j] = quant4_bf16(((const float4*)w)[j]);
  } else if (i < nx4 + nw4 + nb4) {
    int j = i - nx4 - nw4;
    float4 v = ((const float4*)b)[j];
    float4 o;
    o.x = posit_q(v.x); o.y = posit_q(v.y);
    o.z = posit_q(v.z); o.w = posit_q(v.w);
    ((float4*)bq)[j] = o;
  }
}

// ---------------------------------------------------------------------------
// R6: bf16 NT GEMM, 256x256 tile, 8-phase pipelined schedule (T3+T4+T5).
//
// Geometry: BK=64, 512 threads = 8 waves (2M x 4N), 128x64 out per wave,
// LDS 128 KiB = double-buffered A[256][64] + B[256][64] bf16. Grid 8x32 =
// 256 blocks = exactly 1/CU.
//
// Per K-tile: 4 phases x 16 MFMA (quadrants, qm-major). Fragment ds_reads:
// ph1: A rows wm*128+0..63 (8 rd) + B rows wn*64+0..31 (4 rd)
// ph2: B rows wn*64+32..63 (4 rd)          ph3: A rows wm*128+64..127 (8 rd)
// => LDS region last-read phases: A r0/r2 -> ph1, A r1/r3 -> ph3,
//    B r0..r3 -> ph2. Tile t+2 staged into the CURRENT buffer strictly after
//    each region's last read (issue in the following phase, after the
//    all-waves barrier): ph2: A r0,r2 | ph3: B r0..r3 | ph4: A r1,r3.
// Counted wait once per tile at ph4: vmcnt(8) leaves exactly this iter's 8
// issues in flight => tile t+1 (issued last iter) has fully landed. Never
// drains to 0 in steady state; raw s_barrier (not __syncthreads) so the
// compiler never inserts a vmcnt(0) drain.
//
// Swizzle (proven 0-conflict in R3/R5): 16B k-chunk q of row r stored at LDS
// chunk-slot q ^ (r&7); staging pre-swizzles the GLOBAL source so LDS dests
// stay lane-linear as global_load_lds requires.
// ---------------------------------------------------------------------------
__device__ __forceinline__ void gl_lds16(const ushort* g, ushort* l) {
  __builtin_amdgcn_global_load_lds(
      (const __attribute__((address_space(1))) void*)g,
      (__attribute__((address_space(3))) void*)l,
      16, 0, 0);
}

__global__ __launch_bounds__(512, 2) void posit_gemm(
    const ushort* __restrict__ A, const ushort* __restrict__ B,
    const float* __restrict__ bq, float* __restrict__ C,
    int M, int N, int K) {
  __shared__ ushort lds[65536];     // 128 KiB: sA dbuf [0,32K), sB dbuf [32K,64K) elems

  const int tid = threadIdx.x;
  const int wave = tid >> 6;        // 0..7
  const int lane = tid & 63;
  const int wm = wave >> 2;         // 0..1 : 128-row slab
  const int wn = wave & 3;          // 0..3 : 64-col slab
  const int m0 = blockIdx.y << 8;
  const int n0 = blockIdx.x << 8;

  // --- staging: round = 64 rows; thread covers row tid>>3, chunk tid&7,
  // global chunk pre-swizzled by row&7 (== lane>>3, wave/round-independent).
  const int srow = tid >> 3;                      // 0..63
  const int scol = ((tid & 7) ^ (srow & 7)) << 3; // swizzled k-elem offset
  const ushort* Ag = A + (size_t)(m0 + srow) * K + scol;
  const ushort* Bg = B + (size_t)(n0 + srow) * K + scol;
  const size_t rstep = (size_t)64 * K;            // 64 rows per round
  const int ldst = wave << 9;                     // wave*512 elems (HW adds lane*16B)

  ushort* const sA0 = lds;                        // + (t&1)<<14
  ushort* const sB0 = lds + 32768;

  // --- fragment reads
  const int fr = lane & 15;
  const int t4 = lane >> 4;                       // 0..3
  const int swz = fr & 7;

  f32x4 acc[8][4];
#pragma unroll
  for (int i = 0; i < 8; i++)
#pragma unroll
    for (int j = 0; j < 4; j++) acc[i][j] = (f32x4){0.f, 0.f, 0.f, 0.f};

  // ---- prologue: tile0 -> buf0, tile1 -> buf1; wait own tile0 loads only.
#pragma unroll
  for (int r = 0; r < 4; r++) gl_lds16(Ag + r * rstep,      sA0 + (r << 12) + ldst);
#pragma unroll
  for (int r = 0; r < 4; r++) gl_lds16(Bg + r * rstep,      sB0 + (r << 12) + ldst);
#pragma unroll
  for (int r = 0; r < 4; r++) gl_lds16(Ag + 64 + r * rstep, sA0 + 16384 + (r << 12) + ldst);
#pragma unroll
  for (int r = 0; r < 4; r++) gl_lds16(Bg + 64 + r * rstep, sB0 + 16384 + (r << 12) + ldst);
  asm volatile("s_waitcnt vmcnt(8)" ::: "memory");
  __builtin_amdgcn_s_barrier();

  const int T = K >> 6;
  for (int t = 0; t < T; ++t) {
    ushort* const sAb = sA0 + ((t & 1) << 14);
    ushort* const sBb = sB0 + ((t & 1) << 14);
    const bool st = (t + 2) < T;                  // stage tile t+2 (same buffer parity)
    const size_t kt2 = (size_t)(t + 2) << 6;

    bf16x8 fa[4][2], fb[4][2];

    // ---- phase 1: A slab rows +0..63, B slab rows +0..31
#pragma unroll
    for (int i = 0; i < 4; i++)
#pragma unroll
      for (int kk = 0; kk < 2; kk++)
        fa[i][kk] = *(const bf16x8*)(sAb + ((((wm << 7) + (i << 4) + fr) << 6) +
                                            (((kk * 4 + t4) ^ swz) << 3)));
#pragma unroll
    for (int j = 0; j < 2; j++)
#pragma unroll
      for (int kk = 0; kk < 2; kk++)
        fb[j][kk] = *(const bf16x8*)(sBb + ((((wn << 6) + (j << 4) + fr) << 6) +
                                            (((kk * 4 + t4) ^ swz) << 3)));
    __builtin_amdgcn_s_barrier();
    __builtin_amdgcn_s_setprio(1);
#pragma unroll
    for (int kk = 0; kk < 2; kk++)
#pragma unroll
      for (int i = 0; i < 4; i++)
#pragma unroll
        for (int j = 0; j < 2; j++)
          acc[i][j] = __builtin_amdgcn_mfma_f32_16x16x32_bf16(
              fa[i][kk], fb[j][kk], acc[i][j], 0, 0, 0);
    __builtin_amdgcn_s_setprio(0);
    __builtin_amdgcn_s_barrier();

    // ---- phase 2: B slab rows +32..63; stage A rounds 0,2 of t+2
#pragma unroll
    for (int j = 2; j < 4; j++)
#pragma unroll
      for (int kk = 0; kk < 2; kk++)
        fb[j][kk] = *(const bf16x8*)(sBb + ((((wn << 6) + (j << 4) + fr) << 6) +
                                            (((kk * 4 + t4) ^ swz) << 3)));
    if (st) {
      gl_lds16(Ag + kt2 + 0 * rstep, sAb + (0 << 12) + ldst);
      gl_lds16(Ag + kt2 + 2 * rstep, sAb + (2 << 12) + ldst);
    }
    __builtin_amdgcn_s_barrier();
    __builtin_amdgcn_s_setprio(1);
#pragma unroll
    for (int kk = 0; kk < 2; kk++)
#pragma unroll
      for (int i = 0; i < 4; i++)
#pragma unroll
        for (int j = 2; j < 4; j++)
          acc[i][j] = __builtin_amdgcn_mfma_f32_16x16x32_bf16(
              fa[i][kk], fb[j][kk], acc[i][j], 0, 0, 0);
    __builtin_amdgcn_s_setprio(0);
    __builtin_amdgcn_s_barrier();

    // ---- phase 3: A slab rows +64..127; stage B rounds 0..3 of t+2
#pragma unroll
    for (int i = 0; i < 4; i++)
#pragma unroll
      for (int kk = 0; kk < 2; kk++)
        fa[i][kk] = *(const bf16x8*)(sAb + ((((wm << 7) + 64 + (i << 4) + fr) << 6) +
                                            (((kk * 4 + t4) ^ swz) << 3)));
    if (st) {
#pragma unroll
      for (int r = 0; r < 4; r++)
        gl_lds16(Bg + kt2 + r * rstep, sBb + (r << 12) + ldst);
    }
    __builtin_amdgcn_s_barrier();
    __builtin_amdgcn_s_setprio(1);
#pragma unroll
    for (int kk = 0; kk < 2; kk++)
#pragma unroll
      for (int i = 0; i < 4; i++)
#pragma unroll
        for (int j = 0; j < 2; j++)
          acc[i + 4][j] = __builtin_amdgcn_mfma_f32_16x16x32_bf16(
              fa[i][kk], fb[j][kk], acc[i + 4][j], 0, 0, 0);
    __builtin_amdgcn_s_setprio(0);
    __builtin_amdgcn_s_barrier();

    // ---- phase 4: stage A rounds 1,3 of t+2; counted wait (never 0 mid-loop)
    if (st) {
      gl_lds16(Ag + kt2 + 1 * rstep, sAb + (1 << 12) + ldst);
      gl_lds16(Ag + kt2 + 3 * rstep, sAb + (3 << 12) + ldst);
    }
    __builtin_amdgcn_s_barrier();
    __builtin_amdgcn_s_setprio(1);
#pragma unroll
    for (int kk = 0; kk < 2; kk++)
#pragma unroll
      for (int i = 0; i < 4; i++)
#pragma unroll
        for (int j = 2; j < 4; j++)
          acc[i + 4][j] = __builtin_amdgcn_mfma_f32_16x16x32_bf16(
              fa[i][kk], fb[j][kk], acc[i + 4][j], 0, 0, 0);
    __builtin_amdgcn_s_setprio(0);
    if (st) {
      asm volatile("s_waitcnt vmcnt(8)" ::: "memory");   // tile t+1 landed
    } else if (t + 1 < T) {
      asm volatile("s_waitcnt vmcnt(0)" ::: "memory");   // drain final tile
    }
    __builtin_amdgcn_s_barrier();
  }

  // Epilogue: C/D layout col = lane&15, row = (lane>>4)*4 + reg. Fuse bias.
  const int row0 = m0 + (wm << 7) + (t4 << 2);
  const int col0 = n0 + (wn << 6) + fr;
#pragma unroll
  for (int j = 0; j < 4; j++) {
    const int col = col0 + (j << 4);
    const float bv = bq[col];
#pragma unroll
    for (int i = 0; i < 8; i++) {
      const int row = row0 + (i << 4);
#pragma unroll
      for (int r = 0; r < 4; r++)
        C[(size_t)(row + r) * N + col] = acc[i][j][r] + bv;
    }
  }
}

extern "C" void kernel_launch(void* const* d_in, const int* in_sizes, int n_in,
                              void* d_out, int out_size, void* d_ws, size_t ws_size,
                              hipStream_t stream) {
  const float* x = (const float*)d_in[0];
  const float* w = (const float*)d_in[1];
  const float* bias = (const float*)d_in[2];
  float* out = (float*)d_out;

  const int out_f = in_sizes[2];                 // 2048
  const int in_f = in_sizes[1] / out_f;          // 2048
  const int m = in_sizes[0] / in_f;              // 8192
  const int k = in_f;

  // workspace layout: Xq bf16 | Wq bf16 | bq fp32
  ushort* Xq = (ushort*)d_ws;
  ushort* Wq = Xq + (size_t)m * k;
  float* bquant = (float*)(Wq + (size_t)out_f * k);

  const int nx4 = in_sizes[0] / 4;
  const int nw4 = in_sizes[1] / 4;
  const int nb4 = in_sizes[2] / 4;
  const int total4 = nx4 + nw4 + nb4;
  posit_quant_all<<<(total4 + 255) / 256, 256, 0, stream>>>(
      x, w, bias, Xq, Wq, bquant, nx4, nw4, nb4);

  dim3 grid(out_f / 256, m / 256);
  posit_gemm<<<grid, 512, 0, stream>>>(Xq, Wq, bquant, out, m, out_f, k);
}